// Round 11
// baseline (6446.197 us; speedup 1.0000x reference)
//
#include <hip/hip_runtime.h>
#include <hip/hip_bf16.h>

#define TT 256
#define D 1024
#define BD (128 * 1024)
#define NWPL 85
#define NWG 256
#define NUSED 255
#define ROWLEN 1048

typedef __attribute__((ext_vector_type(8))) short bf16x8;
typedef __attribute__((ext_vector_type(4))) float f32x4;

__device__ __forceinline__ unsigned short f2bf(float f) {
    __hip_bfloat16 h = __float2bfloat16(f);
    return *reinterpret_cast<unsigned short*>(&h);
}
__device__ __forceinline__ float bf2f(unsigned short u) {
    unsigned v = (unsigned)u << 16;
    return __builtin_bit_cast(float, v);
}

__global__ __launch_bounds__(256) void cvt_f32_bf16(const float* __restrict__ in,
                                                    unsigned short* __restrict__ out, int n) {
    int i = (blockIdx.x * 256 + threadIdx.x) * 8;
    if (i + 8 <= n) {
        float4 a = *(const float4*)(in + i);
        float4 b = *(const float4*)(in + i + 4);
        unsigned short t[8] = { f2bf(a.x), f2bf(a.y), f2bf(a.z), f2bf(a.w),
                                f2bf(b.x), f2bf(b.y), f2bf(b.z), f2bf(b.w) };
        *(uint4*)(out + i) = *(const uint4*)t;
    }
}

// Persistent point-to-point dataflow dilated-GRU, 8 waves/WG.
// ROUND 11 CHANGE: epilogue stores are PLAIN (L2-allocating) instead of
// agent-scope sc1 (L2-bypass). The release fence before the flag publish
// performs the L2 writeback (buffer_wbl2) => remote visibility; same-XCD
// consumers hit fresh L2 lines => A-broadcast dedups in L2.
__global__ __launch_bounds__(512, 2) void dgru_dataflow(
    const unsigned short* __restrict__ xbf,
    const float* __restrict__ Wih, const float* __restrict__ Whh,
    const float* __restrict__ bih, const float* __restrict__ bhh,
    unsigned short* __restrict__ ring_bf,   // [3][32][BD]
    float* __restrict__ ring_f,             // [3][32][BD]
    unsigned short* __restrict__ hin_ring,  // [2][32][BD]
    float* __restrict__ out,
    unsigned* __restrict__ prog)
{
    __shared__ unsigned short wlds[78 * ROWLEN];

    const int grp = blockIdx.x & 7;
    const int p = 32 * grp + (blockIdx.x >> 3);  // XCD-packing heuristic (perf only)
    if (p >= NUSED) return;
    const int layer = p / NWPL;
    const int u     = p % NWPL;
    const int ncols = (u < 4) ? 13 : 12;
    const int c0    = u * 12 + (u < 4 ? u : 4);

    const int tid = threadIdx.x;

    // ---- one-time: weight slice fp32 -> bf16 -> LDS (stationary); 512 threads
    {
        const float* w0 = Wih + (size_t)layer * 3 * D * D;
        const float* w1 = Whh + (size_t)layer * 3 * D * D;
        const int nrows = 6 * ncols;
        const int rh   = tid >> 8;
        const int t255 = tid & 255;
        for (int rid = rh; rid < nrows; rid += 2) {
            int m   = rid / (3 * ncols);
            int rem = rid - m * 3 * ncols;
            int g   = rem / ncols;
            int c   = rem - g * ncols;
            const float* src = (m ? w1 : w0) + ((size_t)g * D + c0 + c) * D + t255 * 4;
            float4 v = *(const float4*)src;
            ushort4 o = { f2bf(v.x), f2bf(v.y), f2bf(v.z), f2bf(v.w) };
            *(ushort4*)&wlds[rid * ROWLEN + t255 * 4] = o;
        }
        __syncthreads();
    }

    const int wave = tid >> 6;          // 0..7, rows [wave*16, wave*16+16)
    const int lane = tid & 63;
    const int r15  = lane & 15;
    const int kq   = lane >> 4;
    const int kq8  = kq * 8;
    const int c_cl = (r15 < ncols) ? r15 : (ncols - 1);
    const bool cvalid = r15 < ncols;
    const int col  = c0 + c_cl;

    const float bi2 = bih[layer * 3 * D + 2 * D + col];
    const float bh2 = bhh[layer * 3 * D + 2 * D + col];
    const float bs0 = bih[layer * 3 * D + col] + bhh[layer * 3 * D + col];
    const float bs1 = bih[layer * 3 * D + D + col] + bhh[layer * 3 * D + D + col];

    const unsigned short* bp[6];
    #pragma unroll
    for (int mg = 0; mg < 6; ++mg) bp[mg] = wlds + (mg * ncols + c_cl) * ROWLEN;

    const int arow_off = (wave * 16 + r15) * D;

    const int dil = 1 << layer;

    unsigned* pr0 = prog;
    unsigned* pr1 = prog + 128;
    unsigned* pr2 = prog + 256;
    unsigned* myflag = prog + layer * 128 + u;

    const int j2 = (lane < 21) ? lane + 64 : lane;   // lanes cover flags [0,85) x2

    for (int t = 0; t < TT; ++t) {
        // thresholds: hin-ready / hprev-ready / 32-slot back-pressure
        int th1, th2, th3; unsigned *a1, *a2, *a3;
        if (layer == 0)      { a1 = pr0; th1 = t;     a2 = pr1; th2 = t - 30; a3 = pr2; th3 = 0;      }
        else if (layer == 1) { a1 = pr0; th1 = t + 1; a2 = pr1; th2 = t - 1;  a3 = pr2; th3 = t - 30; }
        else                 { a1 = pr1; th1 = t + 1; a2 = pr2; th2 = t - 3;  a3 = pr2; th3 = 0;      }

        if (wave == 0) {
            for (;;) {
                bool ok = true;
                if (th1 > 0) ok = ok && (int)__hip_atomic_load(a1 + lane, __ATOMIC_RELAXED, __HIP_MEMORY_SCOPE_AGENT) >= th1
                                     && (int)__hip_atomic_load(a1 + j2,   __ATOMIC_RELAXED, __HIP_MEMORY_SCOPE_AGENT) >= th1;
                if (th2 > 0) ok = ok && (int)__hip_atomic_load(a2 + lane, __ATOMIC_RELAXED, __HIP_MEMORY_SCOPE_AGENT) >= th2
                                     && (int)__hip_atomic_load(a2 + j2,   __ATOMIC_RELAXED, __HIP_MEMORY_SCOPE_AGENT) >= th2;
                if (th3 > 0) ok = ok && (int)__hip_atomic_load(a3 + lane, __ATOMIC_RELAXED, __HIP_MEMORY_SCOPE_AGENT) >= th3
                                     && (int)__hip_atomic_load(a3 + j2,   __ATOMIC_RELAXED, __HIP_MEMORY_SCOPE_AGENT) >= th3;
                if (__all(ok)) break;
                __builtin_amdgcn_s_sleep(1);
            }
            if ((t & 15) == 0)
                __builtin_amdgcn_fence(__ATOMIC_ACQUIRE, "agent");
        }
        __syncthreads();

        const unsigned short* hinb = layer ? hin_ring + (size_t)((layer - 1) * 32 + (t & 31)) * BD
                                           : xbf + (size_t)t * BD;
        const int rs = (t + 32 - dil) & 31, wsl = t & 31;
        const unsigned short* hprevb = ring_bf + (size_t)(layer * 32 + rs) * BD;
        const float*  hprevf = ring_f + (size_t)(layer * 32 + rs) * BD;
        float*        houtf  = ring_f + (size_t)(layer * 32 + wsl) * BD;
        unsigned short* houtb = ring_bf + (size_t)(layer * 32 + wsl) * BD;

        // ---- epilogue operand prefetch
        float hpv[4], rsv[4];
        #pragma unroll
        for (int q = 0; q < 4; ++q) {
            const int row = wave * 16 + kq * 4 + q;
            const size_t idx = (size_t)row * D + col;
            hpv[q] = hprevf[idx];
            rsv[q] = bf2f(hinb[idx]);
        }

        f32x4 acc[2][3] = {};
        bf16x8 A0[8], A1[8], A2[8];

#define ISSUE1(Av, KS, SL) { \
        Av[(SL) * 2 + 0] = *(const bf16x8*)(hinb   + arow_off + (KS) * 32 + kq8); \
        Av[(SL) * 2 + 1] = *(const bf16x8*)(hprevb + arow_off + (KS) * 32 + kq8); }
#define ISSUEG(Av, BASE) { ISSUE1(Av, (BASE) + 0, 0) ISSUE1(Av, (BASE) + 1, 1) \
                           ISSUE1(Av, (BASE) + 2, 2) ISSUE1(Av, (BASE) + 3, 3) \
                           __builtin_amdgcn_sched_barrier(0); }
#define COMPG(Av, BASE) { _Pragma("unroll") for (int kk = 0; kk < 4; ++kk) { \
        bf16x8 Bv[6]; \
        _Pragma("unroll") for (int mg = 0; mg < 6; ++mg) \
            Bv[mg] = *(const bf16x8*)(bp[mg] + ((BASE) + kk) * 32 + kq8); \
        _Pragma("unroll") for (int g = 0; g < 3; ++g) { \
            acc[0][g] = __builtin_amdgcn_mfma_f32_16x16x32_bf16(Av[kk * 2 + 0], Bv[g],     acc[0][g], 0, 0, 0); \
            acc[1][g] = __builtin_amdgcn_mfma_f32_16x16x32_bf16(Av[kk * 2 + 1], Bv[3 + g], acc[1][g], 0, 0, 0); } } \
        __builtin_amdgcn_sched_barrier(0); }

        ISSUEG(A0, 0);  ISSUEG(A1, 4);  ISSUEG(A2, 8);
        COMPG(A0, 0);   ISSUEG(A0, 12);
        COMPG(A1, 4);   ISSUEG(A1, 16);
        COMPG(A2, 8);   ISSUEG(A2, 20);
        COMPG(A0, 12);  ISSUEG(A0, 24);
        COMPG(A1, 16);  ISSUEG(A1, 28);
        COMPG(A2, 20);
        COMPG(A0, 24);
        COMPG(A1, 28);

        // ---- gates + residual; PLAIN stores (allocate in local L2; release fence
        // below performs the writeback that makes them agent-visible)
        #pragma unroll
        for (int q = 0; q < 4; ++q) {
            const int row = wave * 16 + kq * 4 + q;
            const size_t idx = (size_t)row * D + col;
            float xr = acc[0][0][q] + acc[1][0][q] + bs0;
            float xz = acc[0][1][q] + acc[1][1][q] + bs1;
            float rg = 1.f / (1.f + __expf(-xr));
            float zg = 1.f / (1.f + __expf(-xz));
            float ng = tanhf(acc[0][2][q] + bi2 + rg * (acc[1][2][q] + bh2));
            float hp = hpv[q];
            float h  = (1.f - zg) * ng + zg * hp;
            float v = (h + rsv[q]) * 0.70710678f;
            float y = v > 0.f ? v : 0.2f * v;
            if (cvalid) {
                houtf[idx] = h;
                houtb[idx] = f2bf(h);
                if (layer == 2) {
                    out[(size_t)t * BD + idx] = y;
                } else {
                    hin_ring[(size_t)(layer * 32 + (t & 31)) * BD + idx] = f2bf(y);
                }
            }
        }

        __syncthreads();  // all waves drain vmcnt(0) (stores ack'd at L2) before publish
        if (tid == 0) {
            __builtin_amdgcn_fence(__ATOMIC_RELEASE, "agent");  // wbl2: dirty lines -> MALL
            __hip_atomic_store(myflag, (unsigned)(t + 1), __ATOMIC_RELAXED, __HIP_MEMORY_SCOPE_AGENT);
        }
    }
}

extern "C" void kernel_launch(void* const* d_in, const int* in_sizes, int n_in,
                              void* d_out, int out_size, void* d_ws, size_t ws_size,
                              hipStream_t stream) {
    const float* x   = (const float*)d_in[0];
    const float* Wih = (const float*)d_in[1];
    const float* Whh = (const float*)d_in[2];
    const float* bih = (const float*)d_in[3];
    const float* bhh = (const float*)d_in[4];
    float* out = (float*)d_out;

    char* ws = (char*)d_ws;
    size_t off = 0;
    auto alloc = [&](size_t bytes) -> void* {
        void* p = ws + off;
        off += (bytes + 255) & ~(size_t)255;
        return p;
    };

    const int NX = TT * BD;
    unsigned short* xbf = (unsigned short*)alloc((size_t)NX * 2);  // 67 MB

    size_t zstart = off;
    unsigned short* ring_bf  = (unsigned short*)alloc((size_t)96 * BD * 2);  // 25 MB
    float*          ring_f   = (float*)alloc((size_t)96 * BD * 4);           // 50 MB
    unsigned short* hin_ring = (unsigned short*)alloc((size_t)64 * BD * 2);  // 17 MB
    unsigned*       prog     = (unsigned*)alloc(2048);
    size_t zbytes = off - zstart;

    cvt_f32_bf16<<<NX / 8 / 256, 256, 0, stream>>>(x, xbf, NX);
    hipMemsetAsync(ws + zstart, 0, zbytes, stream);

    dgru_dataflow<<<NWG, 512, 0, stream>>>(
        xbf, Wih, Whh, bih, bhh,
        ring_bf, ring_f, hin_ring, out,
        prog);
}

// Round 12
// 5768.325 us; speedup vs baseline: 1.1175x; 1.1175x over previous
//
#include <hip/hip_runtime.h>
#include <hip/hip_bf16.h>

#define TT 256
#define D 1024
#define BD (128 * 1024)
#define NWPL 85
#define NWG 256
#define NUSED 255
#define ROWLEN 1048

typedef __attribute__((ext_vector_type(8))) short bf16x8;
typedef __attribute__((ext_vector_type(4))) float f32x4;

__device__ __forceinline__ unsigned short f2bf(float f) {
    __hip_bfloat16 h = __float2bfloat16(f);
    return *reinterpret_cast<unsigned short*>(&h);
}
__device__ __forceinline__ float bf2f(unsigned short u) {
    unsigned v = (unsigned)u << 16;
    return __builtin_bit_cast(float, v);
}

__global__ __launch_bounds__(256) void cvt_f32_bf16(const float* __restrict__ in,
                                                    unsigned short* __restrict__ out, int n) {
    int i = (blockIdx.x * 256 + threadIdx.x) * 8;
    if (i + 8 <= n) {
        float4 a = *(const float4*)(in + i);
        float4 b = *(const float4*)(in + i + 4);
        unsigned short t[8] = { f2bf(a.x), f2bf(a.y), f2bf(a.z), f2bf(a.w),
                                f2bf(b.x), f2bf(b.y), f2bf(b.z), f2bf(b.w) };
        *(uint4*)(out + i) = *(const uint4*)t;
    }
}

// ---- asm primitives: MALL-direct loads, manual counted vmcnt ----
#define GLSC16(dst, base, IMM) asm volatile( \
    "global_load_dwordx4 %0, %1, off offset:%2 sc0 sc1" \
    : "=v"(dst) : "v"(base), "i"(IMM))
#define GLSCD(dst, addr) asm volatile( \
    "global_load_dword %0, %1, off sc0 sc1" : "=v"(dst) : "v"(addr))
#define GLSCU(dst, addr) asm volatile( \
    "global_load_ushort %0, %1, off sc0 sc1" : "=v"(dst) : "v"(addr))
#define WAITV(N) { asm volatile("s_waitcnt vmcnt(%0)" :: "i"(N)); \
                   __builtin_amdgcn_sched_barrier(0); }
#define SB __builtin_amdgcn_sched_barrier(0)
#define AGLD(p) __hip_atomic_load((p), __ATOMIC_RELAXED, __HIP_MEMORY_SCOPE_AGENT)
#define AGST(p, v) __hip_atomic_store((p), (v), __ATOMIC_RELAXED, __HIP_MEMORY_SCOPE_AGENT)

// Persistent point-to-point dataflow dilated-GRU, 8 waves/WG, FENCE-FREE.
// All cross-WG reads are sc0sc1 (MALL-direct, always fresh) => L2 is never
// invalidated; weights/bias/x stay cached. A-loads form a REAL 4-deep pipeline
// (asm, manual vmcnt) the compiler cannot collapse: 32 loads in flight/wave.
__global__ __launch_bounds__(512, 2) void dgru_dataflow(
    const unsigned short* __restrict__ xbf,
    const float* __restrict__ Wih, const float* __restrict__ Whh,
    const float* __restrict__ bih, const float* __restrict__ bhh,
    unsigned short* __restrict__ ring_bf,   // [3][8][BD]
    float* __restrict__ ring_f,             // [3][8][BD]
    unsigned short* __restrict__ hin_ring,  // [2][8][BD]
    float* __restrict__ out,
    unsigned* __restrict__ prog)
{
    __shared__ unsigned short wlds[78 * ROWLEN];

    const int grp = blockIdx.x & 7;
    const int p = 32 * grp + (blockIdx.x >> 3);  // XCD-packing heuristic (perf only)
    if (p >= NUSED) return;
    const int layer = p / NWPL;
    const int u     = p % NWPL;
    const int ncols = (u < 4) ? 13 : 12;
    const int c0    = u * 12 + (u < 4 ? u : 4);

    const int tid = threadIdx.x;

    // ---- one-time: weight slice fp32 -> bf16 -> LDS (stationary); 512 threads
    {
        const float* w0 = Wih + (size_t)layer * 3 * D * D;
        const float* w1 = Whh + (size_t)layer * 3 * D * D;
        const int nrows = 6 * ncols;
        const int rh   = tid >> 8;
        const int t255 = tid & 255;
        for (int rid = rh; rid < nrows; rid += 2) {
            int m   = rid / (3 * ncols);
            int rem = rid - m * 3 * ncols;
            int g   = rem / ncols;
            int c   = rem - g * ncols;
            const float* src = (m ? w1 : w0) + ((size_t)g * D + c0 + c) * D + t255 * 4;
            float4 v = *(const float4*)src;
            ushort4 o = { f2bf(v.x), f2bf(v.y), f2bf(v.z), f2bf(v.w) };
            *(ushort4*)&wlds[rid * ROWLEN + t255 * 4] = o;
        }
        __syncthreads();
    }

    const int wave = tid >> 6;          // 0..7, rows [wave*16, wave*16+16)
    const int lane = tid & 63;
    const int r15  = lane & 15;
    const int kq   = lane >> 4;
    const int kq8  = kq * 8;
    const int c_cl = (r15 < ncols) ? r15 : (ncols - 1);
    const bool cvalid = r15 < ncols;
    const int col  = c0 + c_cl;

    const float bi2 = bih[layer * 3 * D + 2 * D + col];
    const float bh2 = bhh[layer * 3 * D + 2 * D + col];
    const float bs0 = bih[layer * 3 * D + col] + bhh[layer * 3 * D + col];
    const float bs1 = bih[layer * 3 * D + D + col] + bhh[layer * 3 * D + D + col];

    const unsigned short* bp[6];
    #pragma unroll
    for (int mg = 0; mg < 6; ++mg) bp[mg] = wlds + (mg * ncols + c_cl) * ROWLEN;

    const int arow_off = (wave * 16 + r15) * D + kq8;

    const int dil = 1 << layer;

    unsigned* pr0 = prog;
    unsigned* pr1 = prog + 128;
    unsigned* pr2 = prog + 256;
    unsigned* myflag = prog + layer * 128 + u;

    const int j2 = (lane < 21) ? lane + 64 : lane;   // lanes cover flags [0,85) x2

    for (int t = 0; t < TT; ++t) {
        // thresholds (8-slot rings): readiness + reuse-distance-8 back-pressure
        int th1, th2, th3; unsigned *a1, *a2, *a3;
        if (layer == 0)      { a1 = pr0; th1 = t;     a2 = pr1; th2 = t - 7; a3 = pr2; th3 = 0;     }
        else if (layer == 1) { a1 = pr0; th1 = t + 1; a2 = pr1; th2 = t - 1; a3 = pr2; th3 = t - 7; }
        else                 { a1 = pr1; th1 = t + 1; a2 = pr2; th2 = t - 3; a3 = pr2; th3 = 0;     }

        if (wave == 0) {
            for (;;) {
                bool ok = true;
                if (th1 > 0) ok = ok && (int)AGLD(a1 + lane) >= th1 && (int)AGLD(a1 + j2) >= th1;
                if (th2 > 0) ok = ok && (int)AGLD(a2 + lane) >= th2 && (int)AGLD(a2 + j2) >= th2;
                if (th3 > 0) ok = ok && (int)AGLD(a3 + lane) >= th3 && (int)AGLD(a3 + j2) >= th3;
                if (__all(ok)) break;
                __builtin_amdgcn_s_sleep(1);
            }
            // NO acquire fence: all cross-WG reads below are sc0sc1 (MALL-direct)
        }
        __syncthreads();

        const unsigned short* hinb = layer ? hin_ring + (size_t)((layer - 1) * 8 + (t & 7)) * BD
                                           : xbf + (size_t)t * BD;
        const int rs = (t + 8 - dil) & 7, wsl = t & 7;
        const unsigned short* hprevb = ring_bf + (size_t)(layer * 8 + rs) * BD;
        const float*  hprevf = ring_f + (size_t)(layer * 8 + rs) * BD;
        float*        houtf  = ring_f + (size_t)(layer * 8 + wsl) * BD;
        unsigned short* houtb = ring_bf + (size_t)(layer * 8 + wsl) * BD;

        const unsigned short* ba_h = hinb + arow_off;
        const unsigned short* ba_p = hprevb + arow_off;

        // ---- epilogue operand prefetch: 8 asm loads, issued FIRST (oldest)
        float hpv[4]; unsigned ru[4];
        {
            #pragma unroll
            for (int q = 0; q < 4; ++q) {
                const int row = wave * 16 + kq * 4 + q;
                const size_t idx = (size_t)row * D + col;
                GLSCD(hpv[q], hprevf + idx);
                GLSCU(ru[q], hinb + idx);
            }
            SB;
        }

        f32x4 acc[2][3] = {};
        bf16x8 A0[8], A1[8], A2[8], A3[8];

#define ISSUE1(Av, KS, SL) { \
        GLSC16(Av[(SL) * 2 + 0], ba_h, (KS) * 64); \
        GLSC16(Av[(SL) * 2 + 1], ba_p, (KS) * 64); }
#define ISSUEG(Av, BASE) { ISSUE1(Av, (BASE) + 0, 0) ISSUE1(Av, (BASE) + 1, 1) \
                           ISSUE1(Av, (BASE) + 2, 2) ISSUE1(Av, (BASE) + 3, 3) \
                           SB; }
#define COMPG(Av, BASE) { _Pragma("unroll") for (int kk = 0; kk < 4; ++kk) { \
        bf16x8 Bv[6]; \
        _Pragma("unroll") for (int mg = 0; mg < 6; ++mg) \
            Bv[mg] = *(const bf16x8*)(bp[mg] + ((BASE) + kk) * 32 + kq8); \
        _Pragma("unroll") for (int g = 0; g < 3; ++g) { \
            acc[0][g] = __builtin_amdgcn_mfma_f32_16x16x32_bf16(Av[kk * 2 + 0], Bv[g],     acc[0][g], 0, 0, 0); \
            acc[1][g] = __builtin_amdgcn_mfma_f32_16x16x32_bf16(Av[kk * 2 + 1], Bv[3 + g], acc[1][g], 0, 0, 0); } } \
        SB; }

        // 4-deep asm pipeline; vmcnt counts are exact (all VMEM here is asm)
        ISSUEG(A0, 0); ISSUEG(A1, 4); ISSUEG(A2, 8); ISSUEG(A3, 12);   // out: 8+32
        WAITV(24); COMPG(A0, 0);  ISSUEG(A0, 16);   // retire epi+g0
        WAITV(24); COMPG(A1, 4);  ISSUEG(A1, 20);
        WAITV(24); COMPG(A2, 8);  ISSUEG(A2, 24);
        WAITV(24); COMPG(A3, 12); ISSUEG(A3, 28);
        WAITV(24); COMPG(A0, 16);
        WAITV(16); COMPG(A1, 20);
        WAITV(8);  COMPG(A2, 24);
        WAITV(0);  COMPG(A3, 28);

        // ---- gates + residual; sc1 stores (MALL-direct; L2 stays clean)
        #pragma unroll
        for (int q = 0; q < 4; ++q) {
            const int row = wave * 16 + kq * 4 + q;
            const size_t idx = (size_t)row * D + col;
            float xr = acc[0][0][q] + acc[1][0][q] + bs0;
            float xz = acc[0][1][q] + acc[1][1][q] + bs1;
            float rg = 1.f / (1.f + __expf(-xr));
            float zg = 1.f / (1.f + __expf(-xz));
            float ng = tanhf(acc[0][2][q] + bi2 + rg * (acc[1][2][q] + bh2));
            float hp = hpv[q];
            float h  = (1.f - zg) * ng + zg * hp;
            float v = (h + bf2f((unsigned short)ru[q])) * 0.70710678f;
            float y = v > 0.f ? v : 0.2f * v;
            if (cvalid) {
                AGST(&houtf[idx], h);
                AGST(&houtb[idx], f2bf(h));
                if (layer == 2) {
                    AGST(&out[(size_t)t * BD + idx], y);
                } else {
                    AGST(&hin_ring[(size_t)(layer * 8 + (t & 7)) * BD + idx], f2bf(y));
                }
            }
        }

        asm volatile("s_waitcnt vmcnt(0)");
        __syncthreads();  // all 8 waves' stores MALL-ack'd before publish
        if (tid == 0) {
            __builtin_amdgcn_fence(__ATOMIC_RELEASE, "agent");
            AGST(myflag, (unsigned)(t + 1));
        }
    }
}

extern "C" void kernel_launch(void* const* d_in, const int* in_sizes, int n_in,
                              void* d_out, int out_size, void* d_ws, size_t ws_size,
                              hipStream_t stream) {
    const float* x   = (const float*)d_in[0];
    const float* Wih = (const float*)d_in[1];
    const float* Whh = (const float*)d_in[2];
    const float* bih = (const float*)d_in[3];
    const float* bhh = (const float*)d_in[4];
    float* out = (float*)d_out;

    char* ws = (char*)d_ws;
    size_t off = 0;
    auto alloc = [&](size_t bytes) -> void* {
        void* p = ws + off;
        off += (bytes + 255) & ~(size_t)255;
        return p;
    };

    const int NX = TT * BD;
    unsigned short* xbf = (unsigned short*)alloc((size_t)NX * 2);  // 67 MB

    size_t zstart = off;
    unsigned short* ring_bf  = (unsigned short*)alloc((size_t)24 * BD * 2);  // 6.3 MB
    float*          ring_f   = (float*)alloc((size_t)24 * BD * 4);           // 12.6 MB
    unsigned short* hin_ring = (unsigned short*)alloc((size_t)16 * BD * 2);  // 4.2 MB
    unsigned*       prog     = (unsigned*)alloc(2048);
    size_t zbytes = off - zstart;

    cvt_f32_bf16<<<NX / 8 / 256, 256, 0, stream>>>(x, xbf, NX);
    hipMemsetAsync(ws + zstart, 0, zbytes, stream);

    dgru_dataflow<<<NWG, 512, 0, stream>>>(
        xbf, Wih, Whh, bih, bhh,
        ring_bf, ring_f, hin_ring, out,
        prog);
}